// Round 1
// baseline (558.731 us; speedup 1.0000x reference)
//
#include <hip/hip_runtime.h>
#include <stdint.h>

// ---------------------------------------------------------------------------
// Batched NT GEMM: C[b][i][j] = sum_k A[b][i][k] * B[b][j][k]
// B=8, M=N=4096, K=128. fp32 in/out. bf16 MFMA 16x16x32.
// v2: single-shot K staging (whole K=128 in LDS, 64 KB), ONE barrier/block
// instead of 8 (4 K-iters x 2), XOR-swizzled LDS (rule #21: linear LDS dest
// via global_load_lds + inverse-swizzled per-lane GLOBAL source + swizzled
// ds_read index) to kill the 16-way bank conflict a 256 B row stride would
// cause. cvt fused into one launch. Output-write bound (~537 MB HBM writes,
// floor ~85-90 us for the GEMM dispatch).
// ---------------------------------------------------------------------------

#define M_DIM 4096
#define N_DIM 4096
#define K_DIM 128

typedef __bf16  bf16x8 __attribute__((ext_vector_type(8)));
typedef float   f32x4  __attribute__((ext_vector_type(4)));

__device__ static inline unsigned short f2bf(float x) {
  union { float f; unsigned int u; } v; v.f = x;
  unsigned int u = v.u;
  unsigned int r = u + 0x7fffu + ((u >> 16) & 1u);   // RNE
  return (unsigned short)(r >> 16);
}

// fp32 -> bf16, 8 elements/thread, BOTH matrices in one launch.
__global__ __launch_bounds__(256) void cvt2_kernel(const float* __restrict__ inA,
                                                   const float* __restrict__ inB,
                                                   unsigned short* __restrict__ outA,
                                                   unsigned short* __restrict__ outB,
                                                   int n8 /* 16B-groups per matrix */) {
  int i = blockIdx.x * 256 + threadIdx.x;
  const float* in;
  unsigned short* out;
  int j = i;
  if (i < n8) {
    in = inA; out = outA;
  } else {
    j = i - n8;
    if (j >= n8) return;
    in = inB; out = outB;
  }
  const float4* p = (const float4*)in;
  float4 a = p[2 * j];
  float4 b = p[2 * j + 1];
  uint4 o;
  o.x = (unsigned)f2bf(a.x) | ((unsigned)f2bf(a.y) << 16);
  o.y = (unsigned)f2bf(a.z) | ((unsigned)f2bf(a.w) << 16);
  o.z = (unsigned)f2bf(b.x) | ((unsigned)f2bf(b.y) << 16);
  o.w = (unsigned)f2bf(b.z) | ((unsigned)f2bf(b.w) << 16);
  ((uint4*)out)[j] = o;
}

// async 16B global -> LDS copy. LDS dest MUST be wave-uniform base + lane*16
// (guaranteed: lds offset = chunk*16, chunk = t*256 + tid). Global source is
// per-lane, so the swizzle lives on the source address (m173 pattern).
__device__ static inline void gl_lds16(const void* g, void* l) {
  __builtin_amdgcn_global_load_lds(
      (const __attribute__((address_space(1))) unsigned int*)g,
      (__attribute__((address_space(3))) unsigned int*)l,
      16, 0, 0);
}

// 128x128 tile, single-shot BK=K=128, 4 waves (2x2), each wave 64x64 =
// 4x4 MFMA 16x16x32 over 4 K-steps. LDS: 2 x 32 KB (row-major [128][128]
// bf16, XOR-swizzled: 16B quad q of row r holds global quad q^(r&7)).
__global__ __launch_bounds__(256) void gemm_bt_bf16(const unsigned short* __restrict__ A,
                                                    const unsigned short* __restrict__ Bm,
                                                    float* __restrict__ C) {
  __shared__ unsigned short As[128 * 128];   // 32 KB
  __shared__ unsigned short Bs[128 * 128];   // 32 KB

  const int tid  = threadIdx.x;
  const int lane = tid & 63;
  const int wid  = tid >> 6;
  const int wm   = wid >> 1;          // wave row (0..1)
  const int wn   = wid & 1;           // wave col (0..1)

  const int bz = blockIdx.z;
  const int bm = blockIdx.y * 128;
  const int bn = blockIdx.x * 128;

  const unsigned short* Ab = A  + (size_t)bz * M_DIM * K_DIM;
  const unsigned short* Bb = Bm + (size_t)bz * N_DIM * K_DIM;
  float*                Cb = C  + (size_t)bz * M_DIM * N_DIM;

  f32x4 acc[4][4] = {};

  const int mrow = lane & 15;         // row within 16-tile
  const int kg   = lane >> 4;         // k-group 0..3, 8 bf16 each

  // ---- stage the ENTIRE K=128 A,B tiles: 2048 chunks of 16B each matrix,
  //      8 chunks/thread/matrix. LDS dest linear; global source quad is
  //      inverse-swizzled so that LDS row r, quad q holds global quad q^(r&7).
  #pragma unroll
  for (int t = 0; t < 8; ++t) {
    int chunk = t * 256 + tid;        // 0..2047
    int row   = chunk >> 4;           // tile row 0..127 (16 quads per 256B row)
    int q     = chunk & 15;           // 16B quad within row
    int qs    = q ^ (row & 7);        // swizzled source quad (involution)
    gl_lds16(Ab + (size_t)(bm + row) * K_DIM + qs * 8, (char*)As + chunk * 16);
    gl_lds16(Bb + (size_t)(bn + row) * K_DIM + qs * 8, (char*)Bs + chunk * 16);
  }
  __syncthreads();   // the ONLY barrier: compiler drains vmcnt here

  // ---- fragments + MFMA. Read index gets the same XOR: ushort index
  //      (row*128 + kk*32 + kg*8) ^ ((row&7)<<3); row&7 == mrow&7 for all
  //      mi (wm*64, mi*16 are multiples of 8), so hoist it.
  const int sx = (mrow & 7) << 3;     // ushort-index xor (bits 3..5)
  #pragma unroll
  for (int kk = 0; kk < 4; ++kk) {
    bf16x8 af[4], bfr[4];
    const int ko = (kk * 32) | (kg * 8);
    const int ks = ko ^ sx;           // stays within the 128-elem row
    #pragma unroll
    for (int mi = 0; mi < 4; ++mi)
      af[mi] = *(const bf16x8*)&As[(wm * 64 + mi * 16 + mrow) * 128 + ks];
    #pragma unroll
    for (int ni = 0; ni < 4; ++ni)
      bfr[ni] = *(const bf16x8*)&Bs[(wn * 64 + ni * 16 + mrow) * 128 + ks];

    #pragma unroll
    for (int mi = 0; mi < 4; ++mi)
      #pragma unroll
      for (int ni = 0; ni < 4; ++ni)
        acc[mi][ni] = __builtin_amdgcn_mfma_f32_16x16x32_bf16(af[mi], bfr[ni],
                                                              acc[mi][ni], 0, 0, 0);
  }

  // ---- epilogue: C/D layout col=lane&15, row=(lane>>4)*4+reg  [m89/m91]
  const int rbase = (lane >> 4) * 4;
  const int col   = lane & 15;
  #pragma unroll
  for (int mi = 0; mi < 4; ++mi) {
    #pragma unroll
    for (int ni = 0; ni < 4; ++ni) {
      int gr = bm + wm * 64 + mi * 16 + rbase;
      int gc = bn + wn * 64 + ni * 16 + col;
      float* cp = Cb + (size_t)gr * N_DIM + gc;
      #pragma unroll
      for (int t = 0; t < 4; ++t)
        cp[(size_t)t * N_DIM] = acc[mi][ni][t];
    }
  }
}

// Insurance path if ws_size is too small for bf16 copies: fp32 vector GEMM.
__global__ void gemm_f32_fallback(const float* __restrict__ A,
                                  const float* __restrict__ B,
                                  float* __restrict__ C) {
  __shared__ float As[16][128];
  __shared__ float Bs2[16][128];
  int tx = threadIdx.x, ty = threadIdx.y;
  int tid = ty * 16 + tx;
  int bz = blockIdx.z;
  int bm = blockIdx.y * 16, bn = blockIdx.x * 16;
  const float* Ab = A + (size_t)bz * M_DIM * K_DIM;
  const float* Bb = B + (size_t)bz * N_DIM * K_DIM;
  for (int i = tid; i < 16 * 128; i += 256) {
    int r = i >> 7, c = i & 127;
    As[r][c]  = Ab[(size_t)(bm + r) * K_DIM + c];
    Bs2[r][c] = Bb[(size_t)(bn + r) * K_DIM + c];
  }
  __syncthreads();
  float s = 0.f;
  #pragma unroll 8
  for (int k = 0; k < 128; ++k) s += As[ty][k] * Bs2[tx][k];
  C[(size_t)bz * M_DIM * N_DIM + (size_t)(bm + ty) * N_DIM + bn + tx] = s;
}

extern "C" void kernel_launch(void* const* d_in, const int* in_sizes, int n_in,
                              void* d_out, int out_size, void* d_ws, size_t ws_size,
                              hipStream_t stream) {
  const float* A  = (const float*)d_in[0];
  const float* Bm = (const float*)d_in[1];
  float*       C  = (float*)d_out;

  const size_t elems    = (size_t)8 * M_DIM * K_DIM;   // 4,194,304 per matrix
  const size_t bf_bytes = elems * 2;                   // 8,388,608 B

  if (ws_size >= 2 * bf_bytes) {
    unsigned short* Abf = (unsigned short*)d_ws;
    unsigned short* Bbf = (unsigned short*)((char*)d_ws + bf_bytes);
    int n8 = (int)(elems >> 3);                        // 524,288 per matrix
    int total = 2 * n8;
    cvt2_kernel<<<(total + 255) / 256, 256, 0, stream>>>(A, Bm, Abf, Bbf, n8);
    dim3 grid(N_DIM / 128, M_DIM / 128, 8);            // 32 x 32 x 8
    gemm_bt_bf16<<<grid, 256, 0, stream>>>(Abf, Bbf, C);
  } else {
    dim3 grid(N_DIM / 16, M_DIM / 16, 8);
    gemm_f32_fallback<<<grid, dim3(16, 16), 0, stream>>>(A, Bm, C);
  }
}